// Round 17
// baseline (113.411 us; speedup 1.0000x reference)
//
#include <hip/hip_runtime.h>
#include <stdint.h>

#define M_DIM 4096
#define N_DIM 4096
#define K_DIM 4096

typedef int i32x4  __attribute__((ext_vector_type(4)));
typedef int i32x16 __attribute__((ext_vector_type(16)));

// ---- Kernel 1: blocks 0..2047: W partial max -> wpmax[b]; blocks 2048..4095:
// 2 x-rows each: rowmax -> xsinv, quant -> xq (single pass, no atomics) ----
__global__ void prep1_kernel(const float* __restrict__ w,
                             const float* __restrict__ x,
                             float* __restrict__ wpmax,
                             char* __restrict__ xq,
                             float* __restrict__ xsinv) {
    __shared__ float sred[4];
    const int t = threadIdx.x;
    if (blockIdx.x < 2048) {
        int tid = blockIdx.x * 256 + t;
        const int stride = 2048 * 256;
        const int n4 = (N_DIM * K_DIM) / 4;
        const float4* w4 = (const float4*)w;
        float m = 0.f;
        for (int i = tid; i < n4; i += stride) {
            float4 a = w4[i];
            m = fmaxf(m, fmaxf(fmaxf(fabsf(a.x), fabsf(a.y)), fmaxf(fabsf(a.z), fabsf(a.w))));
        }
        for (int off = 32; off > 0; off >>= 1) m = fmaxf(m, __shfl_xor(m, off));
        if ((t & 63) == 0) sred[t >> 6] = m;
        __syncthreads();
        if (t == 0)
            wpmax[blockIdx.x] = fmaxf(fmaxf(sred[0], sred[1]), fmaxf(sred[2], sred[3]));
    } else {
        const int rbase = (blockIdx.x - 2048) * 2;
        #pragma unroll
        for (int r = 0; r < 2; ++r) {
            const int row = rbase + r;
            const float4* xr = (const float4*)(x + (size_t)row * K_DIM);
            float4 v[4];
            float m = 0.f;
            #pragma unroll
            for (int i = 0; i < 4; ++i) {
                v[i] = xr[t * 4 + i];
                m = fmaxf(m, fmaxf(fmaxf(fabsf(v[i].x), fabsf(v[i].y)),
                                   fmaxf(fabsf(v[i].z), fabsf(v[i].w))));
            }
            for (int off = 32; off > 0; off >>= 1) m = fmaxf(m, __shfl_xor(m, off));
            if ((t & 63) == 0) sred[t >> 6] = m;
            __syncthreads();
            m = fmaxf(fmaxf(fmaxf(sred[0], sred[1]), fmaxf(sred[2], sred[3])), 1e-30f);
            if (t == 0) xsinv[row] = m * (1.0f / 127.0f);
            const float scale = 127.0f / m;
            int4 o;
            int* op = (int*)&o;
            #pragma unroll
            for (int i = 0; i < 4; ++i) {
                int a = (int)rintf(v[i].x * scale);
                int b = (int)rintf(v[i].y * scale);
                int c = (int)rintf(v[i].z * scale);
                int d = (int)rintf(v[i].w * scale);
                op[i] = (a & 0xff) | ((b & 0xff) << 8) | ((c & 0xff) << 16) | (d << 24);
            }
            *(int4*)(xq + (size_t)row * K_DIM + t * 16) = o;
            __syncthreads();
        }
    }
}

// ---- Kernel 2: every block reduces wpmax (deterministic, L2-hot) -> wscale;
// grid-stride W -> int8 (trunc, exact reference grid); block 0 stores wdq ----
__global__ void prep2_kernel(const float* __restrict__ w,
                             const float* __restrict__ wpmax,
                             int* __restrict__ wq4,
                             float* __restrict__ wdq_out) {
    __shared__ float sred[4];
    const int t = threadIdx.x;
    float m = 0.f;
    #pragma unroll
    for (int i = 0; i < 8; ++i) m = fmaxf(m, wpmax[t * 8 + i]);
    for (int off = 32; off > 0; off >>= 1) m = fmaxf(m, __shfl_xor(m, off));
    if ((t & 63) == 0) sred[t >> 6] = m;
    __syncthreads();
    const float maxv = fmaxf(fmaxf(sred[0], sred[1]), fmaxf(sred[2], sred[3]));
    const float wscale = 127.0f / maxv;
    if (blockIdx.x == 0 && t == 0) *wdq_out = maxv * (1.0f / 127.0f);

    int tid = blockIdx.x * 256 + t;
    const int stride = 2048 * 256;
    const int n4 = (N_DIM * K_DIM) / 4;
    const float4* w4 = (const float4*)w;
    for (int i = tid; i < n4; i += stride) {
        float4 a = w4[i];
        int w0 = (int)fminf(fmaxf(truncf(a.x * wscale), -127.f), 127.f);
        int w1 = (int)fminf(fmaxf(truncf(a.y * wscale), -127.f), 127.f);
        int w2 = (int)fminf(fmaxf(truncf(a.z * wscale), -127.f), 127.f);
        int w3 = (int)fminf(fmaxf(truncf(a.w * wscale), -127.f), 127.f);
        wq4[i] = (w0 & 0xff) | ((w1 & 0xff) << 8) | ((w2 & 0xff) << 16) | (w3 << 24);
    }
}

// ---- Kernel 3: 256x256 i8 GEMM, R6/R13 structure, MFMA = v_mfma_i32_32x32x32_i8
// (half the instructions, 12% higher ceiling vs 16x16x64; same LDS traffic/swizzle).
// 8 waves (2Mx4N) of 128x64; per wave-tile: A 4 m-tiles(32) x 2 halves? -> [h][mt];
// B 2 g-quadrants x 1 n-tile(32). Frags: row/col = lane&31, k-chunk = (lane>>5)*16.
// LDS 128KB: A dbuf @0/32K, B @64K/96K; swizzle byte ^= (row&7)<<4 both-sides
// (k-chunk XOR folds to lb ^ (kk<<5): disjoint-bit identity).
#define BAR()   __builtin_amdgcn_s_barrier()
#define FENCE() __builtin_amdgcn_sched_barrier(0)

#define MFMA32_I8(ACC, AF, BF) \
    asm("v_mfma_i32_32x32x32_i8 %0, %1, %2, %0" : "+v"(ACC) : "v"(AF), "v"(BF))

__global__ __launch_bounds__(512, 2) void gemm_i8(
    const char* __restrict__ A,
    const char* __restrict__ B,
    const float* __restrict__ wdqp,
    const float* __restrict__ xsinv,
    const float* __restrict__ bias,
    float* __restrict__ C)
{
    __shared__ __align__(16) char sM[131072];

    int bid = (blockIdx.x & 7) * 32 + (blockIdx.x >> 3);   // XCD-bijective (nwg=256)
    const int bm = bid >> 4;
    const int bn = bid & 15;

    const int t    = threadIdx.x;
    const int wave = t >> 6;
    const int lane = t & 63;
    const int wm   = wave >> 2;     // 0..1
    const int wn   = wave & 3;      // 0..3

    i32x16 acc[2][2][2] = {};       // [h][g][mt] : 32x32 tiles, 16 regs each

    // Read base: row r = 32-mult + (lane&31); byte = r*128 + slot*16,
    // slot = ((kk<<1)|(lane>>5)) ^ (lane&7)  ==  ((lane>>5)^(lane&7)) ^ (kk<<1)
    // -> byte-in-row = chunk32 ^ (kk<<5), chunk32 = ((lane>>5)^(lane&7))<<4.
    const int chunk32 = (((lane >> 5) ^ (lane & 7)) << 4);
    const int lbA = ((lane & 31) << 7) + chunk32 + wm * 8192;            // + h*16384 + mt*4096
    const int lbB = ((lane & 31) << 7) + chunk32 + wn * 4096 + 65536;    // + g*16384

    // Staging (unchanged from R13): thread t owns linear LDS slot t*16 (+8192);
    // source chunk pre-swizzled so LDS[row][c] = SRC[row][c^(row&7)].
    const int srow = t >> 3;
    const int cch  = (t & 7) ^ (srow & 7);
    const char* Abase = A + (size_t)(bm * 256 + srow) * K_DIM + cch * 16;
    const char* Bbase = B + (size_t)(bn * 256 + srow) * K_DIM + cch * 16;
    const int wave_lds = wave * 1024;   // wave-uniform dest; HW adds lane*16

#define STAGE(SRC, REG, H, KT, BUF) do {                                                \
        const char* _s = SRC + (H) * (128 * K_DIM) + ((KT) << 7);                       \
        char* _d = sM + (REG) + (BUF) * 32768 + (H) * 16384 + wave_lds;                 \
        __builtin_amdgcn_global_load_lds(                                               \
            (const __attribute__((address_space(1))) void*)_s,                          \
            (__attribute__((address_space(3))) void*)_d, 16, 0, 0);                     \
        __builtin_amdgcn_global_load_lds(                                               \
            (const __attribute__((address_space(1))) void*)(_s + (size_t)64 * K_DIM),   \
            (__attribute__((address_space(3))) void*)(_d + 8192), 16, 0, 0);            \
    } while(0)

    // A-frags for half H: [mt][kk] = 8 x ds_read_b128
#define LDA(H, BUF, AF) do {                                                            \
        _Pragma("unroll") for (int mt = 0; mt < 2; ++mt)                                \
        _Pragma("unroll") for (int kk = 0; kk < 4; ++kk)                                \
            AF[mt][kk] = *(const i32x4*)(sM + (BUF)*32768 + (H)*16384 + mt*4096         \
                                            + (lbA ^ (kk << 5)));                      \
    } while(0)

    // B-frags for quadrant G: [kk] = 4 x ds_read_b128
#define LDB(G, BUF, BF) do {                                                            \
        _Pragma("unroll") for (int kk = 0; kk < 4; ++kk)                                \
            BF[kk] = *(const i32x4*)(sM + (BUF)*32768 + (G)*16384 + (lbB ^ (kk << 5))); \
    } while(0)

    // one C-quadrant (64 rows x 32 cols) x K=128: 8 MFMA, kk-outer
#define MMAQ(H, G, AF, BF)                                                              \
        _Pragma("unroll") for (int kk = 0; kk < 4; ++kk)                                \
        _Pragma("unroll") for (int mt = 0; mt < 2; ++mt)                                \
            MFMA32_I8(acc[H][G][mt], AF[mt][kk], BF[kk]);

    // One K-tile: reads from BUF, stages K-tile KN into OBUF, 32 MFMA, 1 barrier.
#define TILE(BUF, OBUF, KN) do {                                                        \
        LDA(0, BUF, af0); LDB(0, BUF, bf0);      /* 12 reads for Q(0,0) */              \
        FENCE();                                                                        \
        LDB(1, BUF, bf1);                        /* 4 reads */                          \
        STAGE(Abase, 0,     0, KN, OBUF);                                               \
        STAGE(Bbase, 65536, 0, KN, OBUF);                                               \
        STAGE(Abase, 0,     1, KN, OBUF);                                               \
        STAGE(Bbase, 65536, 1, KN, OBUF);                                               \
        LDA(1, BUF, af1);                        /* 8 reads */                          \
        FENCE();                                                                        \
        __builtin_amdgcn_s_setprio(1);                                                  \
        MMAQ(0, 0, af0, bf0);                                                           \
        MMAQ(0, 1, af0, bf1);                                                           \
        MMAQ(1, 1, af1, bf1);                                                           \
        MMAQ(1, 0, af1, bf0);                                                           \
        __builtin_amdgcn_s_setprio(0);                                                  \
        asm volatile("s_waitcnt vmcnt(0)");      /* stages issued ~2500cy ago */        \
        BAR();                                                                          \
        FENCE();                                                                        \
    } while(0)

    // Prologue: stage tile 0 -> buf0 only.
    STAGE(Abase, 0,     0, 0, 0);
    STAGE(Bbase, 65536, 0, 0, 0);
    STAGE(Abase, 0,     1, 0, 0);
    STAGE(Bbase, 65536, 1, 0, 0);
    asm volatile("s_waitcnt vmcnt(0)");
    BAR();
    FENCE();

    i32x4 af0[2][4], af1[2][4], bf0[4], bf1[4];

    for (int it = 0; it < 16; ++it) {
        TILE(0, 1, (2 * it + 1) & 31);
        TILE(1, 0, (2 * it + 2) & 31);
    }

    const float wdq = *wdqp;

    // Epilogue: 32x32 D layout (m74/m101): col = lane&31,
    // row = (reg&3) + 8*(reg>>2) + 4*(lane>>5).
    #pragma unroll
    for (int h = 0; h < 2; ++h)
    #pragma unroll
    for (int mt = 0; mt < 2; ++mt) {
        const int grow0 = bm * 256 + h * 128 + wm * 64 + mt * 32 + 4 * (lane >> 5);
        float rs[16];
        #pragma unroll
        for (int rg = 0; rg < 16; ++rg)
            rs[rg] = xsinv[grow0 + (rg & 3) + 8 * (rg >> 2)] * wdq;
        #pragma unroll
        for (int g = 0; g < 2; ++g) {
            const int gcol = bn * 256 + g * 128 + wn * 32 + (lane & 31);
            const float bv = bias[gcol];
            #pragma unroll
            for (int rg = 0; rg < 16; ++rg) {
                const int grow = grow0 + (rg & 3) + 8 * (rg >> 2);
                C[(size_t)grow * N_DIM + gcol] = (float)acc[h][g][mt][rg] * rs[rg] + bv;
            }
        }
    }

#undef STAGE
#undef LDA
#undef LDB
#undef MMAQ
#undef TILE
}

extern "C" void kernel_launch(void* const* d_in, const int* in_sizes, int n_in,
                              void* d_out, int out_size, void* d_ws, size_t ws_size,
                              hipStream_t stream) {
    const float* x    = (const float*)d_in[0];   // [4096, 4096]
    const float* w    = (const float*)d_in[1];   // [4096, 4096]
    const float* bias = (const float*)d_in[2];   // [4096]
    float* out = (float*)d_out;

    float* wpmax = (float*)d_ws;                            // [2048] partial maxima
    float* wdqp  = (float*)((char*)d_ws + 8192);            // [1] wmax/127
    float* xsinv = (float*)((char*)d_ws + 8448);            // [4096]
    char*  xq    = (char*)d_ws + 32768;                     // 16 MB
    char*  wq    = (char*)d_ws + 32768 + (size_t)M_DIM * K_DIM;

    prep1_kernel<<<4096, 256, 0, stream>>>(w, x, wpmax, xq, xsinv);
    prep2_kernel<<<2048, 256, 0, stream>>>(w, wpmax, (int*)wq, wdqp);

    const int grid = (M_DIM / 256) * (N_DIM / 256);  // 256
    gemm_i8<<<grid, 512, 0, stream>>>(xq, wq, wdqp, xsinv, bias, out);
}

// Round 18
// 112.921 us; speedup vs baseline: 1.0043x; 1.0043x over previous
//
#include <hip/hip_runtime.h>
#include <stdint.h>

#define M_DIM 4096
#define N_DIM 4096
#define K_DIM 4096

typedef int i32x4  __attribute__((ext_vector_type(4)));
typedef int i32x16 __attribute__((ext_vector_type(16)));

// ---- Kernel 1: blocks 0..2047: W partial max -> wpmax[b]; blocks 2048..4095:
// 2 x-rows each: rowmax -> xsinv, quant -> xq (single pass, no atomics) ----
__global__ void prep1_kernel(const float* __restrict__ w,
                             const float* __restrict__ x,
                             float* __restrict__ wpmax,
                             char* __restrict__ xq,
                             float* __restrict__ xsinv) {
    __shared__ float sred[4];
    const int t = threadIdx.x;
    if (blockIdx.x < 2048) {
        int tid = blockIdx.x * 256 + t;
        const int stride = 2048 * 256;
        const int n4 = (N_DIM * K_DIM) / 4;
        const float4* w4 = (const float4*)w;
        float m = 0.f;
        for (int i = tid; i < n4; i += stride) {
            float4 a = w4[i];
            m = fmaxf(m, fmaxf(fmaxf(fabsf(a.x), fabsf(a.y)), fmaxf(fabsf(a.z), fabsf(a.w))));
        }
        for (int off = 32; off > 0; off >>= 1) m = fmaxf(m, __shfl_xor(m, off));
        if ((t & 63) == 0) sred[t >> 6] = m;
        __syncthreads();
        if (t == 0)
            wpmax[blockIdx.x] = fmaxf(fmaxf(sred[0], sred[1]), fmaxf(sred[2], sred[3]));
    } else {
        const int rbase = (blockIdx.x - 2048) * 2;
        #pragma unroll
        for (int r = 0; r < 2; ++r) {
            const int row = rbase + r;
            const float4* xr = (const float4*)(x + (size_t)row * K_DIM);
            float4 v[4];
            float m = 0.f;
            #pragma unroll
            for (int i = 0; i < 4; ++i) {
                v[i] = xr[t * 4 + i];
                m = fmaxf(m, fmaxf(fmaxf(fabsf(v[i].x), fabsf(v[i].y)),
                                   fmaxf(fabsf(v[i].z), fabsf(v[i].w))));
            }
            for (int off = 32; off > 0; off >>= 1) m = fmaxf(m, __shfl_xor(m, off));
            if ((t & 63) == 0) sred[t >> 6] = m;
            __syncthreads();
            m = fmaxf(fmaxf(fmaxf(sred[0], sred[1]), fmaxf(sred[2], sred[3])), 1e-30f);
            if (t == 0) xsinv[row] = m * (1.0f / 127.0f);
            const float scale = 127.0f / m;
            int4 o;
            int* op = (int*)&o;
            #pragma unroll
            for (int i = 0; i < 4; ++i) {
                int a = (int)rintf(v[i].x * scale);
                int b = (int)rintf(v[i].y * scale);
                int c = (int)rintf(v[i].z * scale);
                int d = (int)rintf(v[i].w * scale);
                op[i] = (a & 0xff) | ((b & 0xff) << 8) | ((c & 0xff) << 16) | (d << 24);
            }
            *(int4*)(xq + (size_t)row * K_DIM + t * 16) = o;
            __syncthreads();
        }
    }
}

// ---- Kernel 2: every block reduces wpmax (deterministic, L2-hot) -> wscale;
// grid-stride W -> int8 (trunc, exact reference grid); block 0 stores wdq ----
__global__ void prep2_kernel(const float* __restrict__ w,
                             const float* __restrict__ wpmax,
                             int* __restrict__ wq4,
                             float* __restrict__ wdq_out) {
    __shared__ float sred[4];
    const int t = threadIdx.x;
    float m = 0.f;
    #pragma unroll
    for (int i = 0; i < 8; ++i) m = fmaxf(m, wpmax[t * 8 + i]);
    for (int off = 32; off > 0; off >>= 1) m = fmaxf(m, __shfl_xor(m, off));
    if ((t & 63) == 0) sred[t >> 6] = m;
    __syncthreads();
    const float maxv = fmaxf(fmaxf(sred[0], sred[1]), fmaxf(sred[2], sred[3]));
    const float wscale = 127.0f / maxv;
    if (blockIdx.x == 0 && t == 0) *wdq_out = maxv * (1.0f / 127.0f);

    int tid = blockIdx.x * 256 + t;
    const int stride = 2048 * 256;
    const int n4 = (N_DIM * K_DIM) / 4;
    const float4* w4 = (const float4*)w;
    for (int i = tid; i < n4; i += stride) {
        float4 a = w4[i];
        int w0 = (int)fminf(fmaxf(truncf(a.x * wscale), -127.f), 127.f);
        int w1 = (int)fminf(fmaxf(truncf(a.y * wscale), -127.f), 127.f);
        int w2 = (int)fminf(fmaxf(truncf(a.z * wscale), -127.f), 127.f);
        int w3 = (int)fminf(fmaxf(truncf(a.w * wscale), -127.f), 127.f);
        wq4[i] = (w0 & 0xff) | ((w1 & 0xff) << 8) | ((w2 & 0xff) << 16) | (w3 << 24);
    }
}

// ---- Kernel 3: 256x256 i8 GEMM, R6/R13 structure, MFMA = v_mfma_i32_32x32x32_i8
// (half the instructions, 12% higher ceiling vs 16x16x64; same LDS traffic/swizzle).
// 8 waves (2Mx4N) of 128x64; per wave-tile: A 4 m-tiles(32) x 2 halves? -> [h][mt];
// B 2 g-quadrants x 1 n-tile(32). Frags: row/col = lane&31, k-chunk = (lane>>5)*16.
// LDS 128KB: A dbuf @0/32K, B @64K/96K; swizzle byte ^= (row&7)<<4 both-sides
// (k-chunk XOR folds to lb ^ (kk<<5): disjoint-bit identity).
#define BAR()   __builtin_amdgcn_s_barrier()
#define FENCE() __builtin_amdgcn_sched_barrier(0)

#define MFMA32_I8(ACC, AF, BF) \
    asm("v_mfma_i32_32x32x32_i8 %0, %1, %2, %0" : "+v"(ACC) : "v"(AF), "v"(BF))

__global__ __launch_bounds__(512, 2) void gemm_i8(
    const char* __restrict__ A,
    const char* __restrict__ B,
    const float* __restrict__ wdqp,
    const float* __restrict__ xsinv,
    const float* __restrict__ bias,
    float* __restrict__ C)
{
    __shared__ __align__(16) char sM[131072];

    int bid = (blockIdx.x & 7) * 32 + (blockIdx.x >> 3);   // XCD-bijective (nwg=256)
    const int bm = bid >> 4;
    const int bn = bid & 15;

    const int t    = threadIdx.x;
    const int wave = t >> 6;
    const int lane = t & 63;
    const int wm   = wave >> 2;     // 0..1
    const int wn   = wave & 3;      // 0..3

    i32x16 acc[2][2][2] = {};       // [h][g][mt] : 32x32 tiles, 16 regs each

    // Read base: row r = 32-mult + (lane&31); byte = r*128 + slot*16,
    // slot = ((kk<<1)|(lane>>5)) ^ (lane&7)  ==  ((lane>>5)^(lane&7)) ^ (kk<<1)
    // -> byte-in-row = chunk32 ^ (kk<<5), chunk32 = ((lane>>5)^(lane&7))<<4.
    const int chunk32 = (((lane >> 5) ^ (lane & 7)) << 4);
    const int lbA = ((lane & 31) << 7) + chunk32 + wm * 8192;            // + h*16384 + mt*4096
    const int lbB = ((lane & 31) << 7) + chunk32 + wn * 4096 + 65536;    // + g*16384

    // Staging (unchanged from R13): thread t owns linear LDS slot t*16 (+8192);
    // source chunk pre-swizzled so LDS[row][c] = SRC[row][c^(row&7)].
    const int srow = t >> 3;
    const int cch  = (t & 7) ^ (srow & 7);
    const char* Abase = A + (size_t)(bm * 256 + srow) * K_DIM + cch * 16;
    const char* Bbase = B + (size_t)(bn * 256 + srow) * K_DIM + cch * 16;
    const int wave_lds = wave * 1024;   // wave-uniform dest; HW adds lane*16

#define STAGE(SRC, REG, H, KT, BUF) do {                                                \
        const char* _s = SRC + (H) * (128 * K_DIM) + ((KT) << 7);                       \
        char* _d = sM + (REG) + (BUF) * 32768 + (H) * 16384 + wave_lds;                 \
        __builtin_amdgcn_global_load_lds(                                               \
            (const __attribute__((address_space(1))) void*)_s,                          \
            (__attribute__((address_space(3))) void*)_d, 16, 0, 0);                     \
        __builtin_amdgcn_global_load_lds(                                               \
            (const __attribute__((address_space(1))) void*)(_s + (size_t)64 * K_DIM),   \
            (__attribute__((address_space(3))) void*)(_d + 8192), 16, 0, 0);            \
    } while(0)

    // A-frags for half H: [mt][kk] = 8 x ds_read_b128
#define LDA(H, BUF, AF) do {                                                            \
        _Pragma("unroll") for (int mt = 0; mt < 2; ++mt)                                \
        _Pragma("unroll") for (int kk = 0; kk < 4; ++kk)                                \
            AF[mt][kk] = *(const i32x4*)(sM + (BUF)*32768 + (H)*16384 + mt*4096         \
                                            + (lbA ^ (kk << 5)));                      \
    } while(0)

    // B-frags for quadrant G: [kk] = 4 x ds_read_b128
#define LDB(G, BUF, BF) do {                                                            \
        _Pragma("unroll") for (int kk = 0; kk < 4; ++kk)                                \
            BF[kk] = *(const i32x4*)(sM + (BUF)*32768 + (G)*16384 + (lbB ^ (kk << 5))); \
    } while(0)

    // one C-quadrant (64 rows x 32 cols) x K=128: 8 MFMA, kk-outer
#define MMAQ(H, G, AF, BF)                                                              \
        _Pragma("unroll") for (int kk = 0; kk < 4; ++kk)                                \
        _Pragma("unroll") for (int mt = 0; mt < 2; ++mt)                                \
            MFMA32_I8(acc[H][G][mt], AF[mt][kk], BF[kk]);

    // One K-tile: reads from BUF, stages K-tile KN into OBUF, 32 MFMA, 1 barrier.
#define TILE(BUF, OBUF, KN) do {                                                        \
        LDA(0, BUF, af0); LDB(0, BUF, bf0);      /* 12 reads for Q(0,0) */              \
        FENCE();                                                                        \
        LDB(1, BUF, bf1);                        /* 4 reads */                          \
        STAGE(Abase, 0,     0, KN, OBUF);                                               \
        STAGE(Bbase, 65536, 0, KN, OBUF);                                               \
        STAGE(Abase, 0,     1, KN, OBUF);                                               \
        STAGE(Bbase, 65536, 1, KN, OBUF);                                               \
        LDA(1, BUF, af1);                        /* 8 reads */                          \
        FENCE();                                                                        \
        __builtin_amdgcn_s_setprio(1);                                                  \
        MMAQ(0, 0, af0, bf0);                                                           \
        MMAQ(0, 1, af0, bf1);                                                           \
        MMAQ(1, 1, af1, bf1);                                                           \
        MMAQ(1, 0, af1, bf0);                                                           \
        __builtin_amdgcn_s_setprio(0);                                                  \
        asm volatile("s_waitcnt vmcnt(0)");      /* stages issued ~2500cy ago */        \
        BAR();                                                                          \
        FENCE();                                                                        \
    } while(0)

    // Prologue: stage tile 0 -> buf0 only.
    STAGE(Abase, 0,     0, 0, 0);
    STAGE(Bbase, 65536, 0, 0, 0);
    STAGE(Abase, 0,     1, 0, 0);
    STAGE(Bbase, 65536, 1, 0, 0);
    asm volatile("s_waitcnt vmcnt(0)");
    BAR();
    FENCE();

    i32x4 af0[2][4], af1[2][4], bf0[4], bf1[4];

    for (int it = 0; it < 16; ++it) {
        TILE(0, 1, (2 * it + 1) & 31);
        TILE(1, 0, (2 * it + 2) & 31);
    }

    const float wdq = *wdqp;

    // Epilogue: 32x32 D layout (m74/m101): col = lane&31,
    // row = (reg&3) + 8*(reg>>2) + 4*(lane>>5).
    #pragma unroll
    for (int h = 0; h < 2; ++h)
    #pragma unroll
    for (int mt = 0; mt < 2; ++mt) {
        const int grow0 = bm * 256 + h * 128 + wm * 64 + mt * 32 + 4 * (lane >> 5);
        float rs[16];
        #pragma unroll
        for (int rg = 0; rg < 16; ++rg)
            rs[rg] = xsinv[grow0 + (rg & 3) + 8 * (rg >> 2)] * wdq;
        #pragma unroll
        for (int g = 0; g < 2; ++g) {
            const int gcol = bn * 256 + g * 128 + wn * 32 + (lane & 31);
            const float bv = bias[gcol];
            #pragma unroll
            for (int rg = 0; rg < 16; ++rg) {
                const int grow = grow0 + (rg & 3) + 8 * (rg >> 2);
                C[(size_t)grow * N_DIM + gcol] = (float)acc[h][g][mt][rg] * rs[rg] + bv;
            }
        }
    }

#undef STAGE
#undef LDA
#undef LDB
#undef MMAQ
#undef TILE
}

extern "C" void kernel_launch(void* const* d_in, const int* in_sizes, int n_in,
                              void* d_out, int out_size, void* d_ws, size_t ws_size,
                              hipStream_t stream) {
    const float* x    = (const float*)d_in[0];   // [4096, 4096]
    const float* w    = (const float*)d_in[1];   // [4096, 4096]
    const float* bias = (const float*)d_in[2];   // [4096]
    float* out = (float*)d_out;

    float* wpmax = (float*)d_ws;                            // [2048] partial maxima
    float* wdqp  = (float*)((char*)d_ws + 8192);            // [1] wmax/127
    float* xsinv = (float*)((char*)d_ws + 8448);            // [4096]
    char*  xq    = (char*)d_ws + 32768;                     // 16 MB
    char*  wq    = (char*)d_ws + 32768 + (size_t)M_DIM * K_DIM;

    prep1_kernel<<<4096, 256, 0, stream>>>(w, x, wpmax, xq, xsinv);
    prep2_kernel<<<2048, 256, 0, stream>>>(w, wpmax, (int*)wq, wdqp);

    const int grid = (M_DIM / 256) * (N_DIM / 256);  // 256
    gemm_i8<<<grid, 512, 0, stream>>>(xq, wq, wdqp, xsinv, bias, out);
}